// Round 1
// baseline (2162.144 us; speedup 1.0000x reference)
//
#include <hip/hip_runtime.h>

#define N_NODES 250000
#define N_EDGES 4000000
#define DIM 64

// ---------------- workspace layout (bytes) ----------------
// [0        , 1'000'000)  deg      int[250000]   (memset 0)
// [1'000'000, 2'000'000)  fill     int[250000]   (memset 0)
// [2'000'000, 3'000'000)  row_ptr  int[250000]
// [3'000'000, 4'000'000)  dis      float[250000]
// [4'000'000,20'000'000)  csr_col  int[4000000]

__global__ void count_deg(const int* __restrict__ row, int* __restrict__ deg) {
    int e = blockIdx.x * blockDim.x + threadIdx.x;
    if (e < N_EDGES) atomicAdd(&deg[row[e]], 1);
}

__global__ void compute_dis(const int* __restrict__ deg, float* __restrict__ dis) {
    int i = blockIdx.x * blockDim.x + threadIdx.x;
    if (i < N_NODES) {
        // +1 for the self-loop edge (so deg >= 1 always)
        dis[i] = rsqrtf((float)(deg[i] + 1));
    }
}

// single-block exclusive scan of deg[] -> row_ptr[] (CSR offsets for real edges only)
__global__ __launch_bounds__(1024) void scan_rowptr(const int* __restrict__ deg,
                                                    int* __restrict__ row_ptr) {
    const int T = 1024;
    const int chunk = (N_NODES + T - 1) / T;  // 245
    int t = threadIdx.x;
    int beg = t * chunk;
    int end = beg + chunk; if (end > N_NODES) end = N_NODES;
    int s = 0;
    for (int i = beg; i < end; ++i) s += deg[i];
    __shared__ int sm[T];
    sm[t] = s;
    __syncthreads();
    for (int off = 1; off < T; off <<= 1) {
        int v = (t >= off) ? sm[t - off] : 0;
        __syncthreads();
        sm[t] += v;
        __syncthreads();
    }
    int run = sm[t] - s;  // exclusive prefix of this thread's chunk
    for (int i = beg; i < end; ++i) { row_ptr[i] = run; run += deg[i]; }
}

__global__ void fill_csr(const int* __restrict__ row, const int* __restrict__ col,
                         const int* __restrict__ row_ptr, int* __restrict__ fill,
                         int* __restrict__ csr_col) {
    int e = blockIdx.x * blockDim.x + threadIdx.x;
    if (e < N_EDGES) {
        int r = row[e];
        int pos = row_ptr[r] + atomicAdd(&fill[r], 1);
        csr_col[pos] = col[e];
    }
}

// one 64-lane wave per row, lane = feature dim; 4 rows per 256-thread block.
// out[r] = dis[r] * ( dis[r]*fin[r] + sum_{c in N(r)} dis[c]*fin[c] )
__global__ __launch_bounds__(256) void spmm(const int* __restrict__ row_ptr,
                                            const int* __restrict__ deg,
                                            const int* __restrict__ csr_col,
                                            const float* __restrict__ dis,
                                            const float* __restrict__ fin, int in_stride, int in_off,
                                            float* __restrict__ fout, int out_stride, int out_off,
                                            float* __restrict__ fout2) {
    int lane = threadIdx.x & 63;
    int r = blockIdx.x * 4 + (threadIdx.x >> 6);
    if (r >= N_NODES) return;
    float dr  = dis[r];
    float acc = dr * fin[(size_t)r * in_stride + in_off + lane];  // self-loop term
    int start = row_ptr[r];
    int cnt   = deg[r];
    for (int j = 0; j < cnt; ++j) {
        int c = csr_col[start + j];
        acc += dis[c] * fin[(size_t)c * in_stride + in_off + lane];
    }
    float v = dr * acc;
    fout[(size_t)r * out_stride + out_off + lane] = v;
    if (fout2) fout2[(size_t)r * DIM + lane] = v;
}

extern "C" void kernel_launch(void* const* d_in, const int* in_sizes, int n_in,
                              void* d_out, int out_size, void* d_ws, size_t ws_size,
                              hipStream_t stream) {
    const int*   ei  = (const int*)d_in[0];     // edge_index [2, 4M]
    const float* emb = (const float*)d_in[1];   // [250000, 64]
    const int* row = ei;
    const int* col = ei + N_EDGES;
    float* out = (float*)d_out;

    char* ws = (char*)d_ws;
    int*   deg     = (int*)(ws + 0);
    int*   fill    = (int*)(ws + 1000000);
    int*   row_ptr = (int*)(ws + 2000000);
    float* dis     = (float*)(ws + 3000000);
    int*   csr_col = (int*)(ws + 4000000);

    // zero deg + fill (adjacent, one memset)
    hipMemsetAsync(ws, 0, 2000000, stream);

    const int TB = 256;
    count_deg  <<<(N_EDGES + TB - 1) / TB, TB, 0, stream>>>(row, deg);
    compute_dis<<<(N_NODES + TB - 1) / TB, TB, 0, stream>>>(deg, dis);
    scan_rowptr<<<1, 1024, 0, stream>>>(deg, row_ptr);
    fill_csr   <<<(N_EDGES + TB - 1) / TB, TB, 0, stream>>>(row, col, row_ptr, fill, csr_col);

    // output layout: all_feat[i, slot, :] with slot0 = layer3, slot1 = layer1,
    // slot2 = layer2; then final feat (= layer3) at offset 48'000'000.
    int spmm_blocks = (N_NODES + 3) / 4;
    // layer 1: emb -> slot 1
    spmm<<<spmm_blocks, TB, 0, stream>>>(row_ptr, deg, csr_col, dis,
                                         emb, DIM, 0,
                                         out, 3 * DIM, DIM, nullptr);
    // layer 2: slot 1 -> slot 2
    spmm<<<spmm_blocks, TB, 0, stream>>>(row_ptr, deg, csr_col, dis,
                                         out, 3 * DIM, DIM,
                                         out, 3 * DIM, 2 * DIM, nullptr);
    // layer 3: slot 2 -> slot 0  (+ second output)
    spmm<<<spmm_blocks, TB, 0, stream>>>(row_ptr, deg, csr_col, dis,
                                         out, 3 * DIM, 2 * DIM,
                                         out, 3 * DIM, 0, out + 48000000);
}

// Round 2
// 1196.978 us; speedup vs baseline: 1.8063x; 1.8063x over previous
//
#include <hip/hip_runtime.h>

#define N_NODES 250000
#define N_EDGES 4000000
#define DIM 64

// ---------------- workspace layout (bytes) ----------------
// [0        , 1'000'000)  deg      int[250000]   (memset 0)
// [1'000'000, 2'000'000)  fill     int[250000]   (memset 0)
// [2'000'000, 3'000'000)  row_ptr  int[250000]
// [3'000'000, 4'000'000)  dis      float[250000]
// [4'000'000,20'000'000)  csr_col  int[4000000]

__device__ __forceinline__ int bcast_i(int v, int l) {
    return __builtin_amdgcn_readlane(v, l);
}
__device__ __forceinline__ float bcast_f(float v, int l) {
    return __uint_as_float(__builtin_amdgcn_readlane(__float_as_uint(v), l));
}

__global__ void count_deg(const int* __restrict__ row, int* __restrict__ deg) {
    int e4 = blockIdx.x * blockDim.x + threadIdx.x;
    if (e4 < N_EDGES / 4) {
        int4 r = ((const int4*)row)[e4];
        atomicAdd(&deg[r.x], 1);
        atomicAdd(&deg[r.y], 1);
        atomicAdd(&deg[r.z], 1);
        atomicAdd(&deg[r.w], 1);
    }
}

__global__ void compute_dis(const int* __restrict__ deg, float* __restrict__ dis) {
    int i = blockIdx.x * blockDim.x + threadIdx.x;
    if (i < N_NODES) dis[i] = rsqrtf((float)(deg[i] + 1));  // +1 self-loop
}

// single-block exclusive scan of deg[] -> row_ptr[], int4-vectorized
__global__ __launch_bounds__(1024) void scan_rowptr(const int* __restrict__ deg,
                                                    int* __restrict__ row_ptr) {
    const int T = 1024;
    const int N4 = N_NODES / 4;        // 62500
    const int C4 = (N4 + T - 1) / T;   // 62 int4s per thread
    int t = threadIdx.x;
    int b4 = t * C4;
    int e4 = b4 + C4; if (e4 > N4) e4 = N4;
    const int4* d4 = (const int4*)deg;
    int s = 0;
#pragma unroll 4
    for (int i = b4; i < e4; ++i) {
        int4 v = d4[i];
        s += v.x + v.y + v.z + v.w;
    }
    __shared__ int sm[T];
    sm[t] = s;
    __syncthreads();
    for (int off = 1; off < T; off <<= 1) {
        int v = (t >= off) ? sm[t - off] : 0;
        __syncthreads();
        sm[t] += v;
        __syncthreads();
    }
    int run = sm[t] - s;
    int4* rp4 = (int4*)row_ptr;
#pragma unroll 4
    for (int i = b4; i < e4; ++i) {
        int4 v = d4[i];
        int4 o;
        o.x = run;
        o.y = o.x + v.x;
        o.z = o.y + v.y;
        o.w = o.z + v.z;
        run = o.w + v.w;
        rp4[i] = o;
    }
}

__global__ void fill_csr(const int* __restrict__ row, const int* __restrict__ col,
                         const int* __restrict__ row_ptr, int* __restrict__ fill,
                         int* __restrict__ csr_col) {
    int e4 = blockIdx.x * blockDim.x + threadIdx.x;
    if (e4 < N_EDGES / 4) {
        int4 r = ((const int4*)row)[e4];
        int4 c = ((const int4*)col)[e4];
        int p;
        p = row_ptr[r.x] + atomicAdd(&fill[r.x], 1); csr_col[p] = c.x;
        p = row_ptr[r.y] + atomicAdd(&fill[r.y], 1); csr_col[p] = c.y;
        p = row_ptr[r.z] + atomicAdd(&fill[r.z], 1); csr_col[p] = c.z;
        p = row_ptr[r.w] + atomicAdd(&fill[r.w], 1); csr_col[p] = c.w;
    }
}

// one 64-lane wave per row, lane = feature dim; 4 rows per 256-thread block.
// out[r] = dis[r] * ( dis[r]*fin[r] + sum_{c in N(r)} dis[c]*fin[c] )
// MLP strategy: per 64-edge batch, coalesced-load cols + gather weights once,
// broadcast via v_readlane (register, no memory), unroll feature gathers x8
// with zero-weight padding (dead lanes load row 0 -> L1 hit).
__global__ __launch_bounds__(256) void spmm(const int* __restrict__ row_ptr,
                                            const int* __restrict__ deg,
                                            const int* __restrict__ csr_col,
                                            const float* __restrict__ dis,
                                            const float* __restrict__ fin, int in_stride, int in_off,
                                            float* __restrict__ fout, int out_stride, int out_off,
                                            float* __restrict__ fout2) {
    int lane = threadIdx.x & 63;
    int r = blockIdx.x * 4 + (threadIdx.x >> 6);
    if (r >= N_NODES) return;
    const float* fin_l = fin + in_off + lane;
    float dr  = dis[r];
    float acc = dr * fin_l[(size_t)r * in_stride];  // self-loop term
    int start = row_ptr[r];
    int cnt   = deg[r];
    for (int base = 0; base < cnt; base += 64) {
        int m = cnt - base; if (m > 64) m = 64;
        int cl = 0; float wl = 0.f;
        if (lane < m) {
            cl = csr_col[start + base + lane];
            wl = dis[cl];
        }
        int m8 = (m + 7) & ~7;
        for (int j = 0; j < m8; j += 8) {
            float f[8], w[8];
#pragma unroll
            for (int u = 0; u < 8; ++u) {
                int c = bcast_i(cl, j + u);
                w[u]  = bcast_f(wl, j + u);
                f[u]  = fin_l[(size_t)(c * in_stride)];
            }
#pragma unroll
            for (int u = 0; u < 8; ++u) acc += w[u] * f[u];
        }
    }
    float v = dr * acc;
    fout[(size_t)r * out_stride + out_off + lane] = v;
    if (fout2) fout2[(size_t)r * DIM + lane] = v;
}

extern "C" void kernel_launch(void* const* d_in, const int* in_sizes, int n_in,
                              void* d_out, int out_size, void* d_ws, size_t ws_size,
                              hipStream_t stream) {
    const int*   ei  = (const int*)d_in[0];     // edge_index [2, 4M]
    const float* emb = (const float*)d_in[1];   // [250000, 64]
    const int* row = ei;
    const int* col = ei + N_EDGES;
    float* out = (float*)d_out;

    char* ws = (char*)d_ws;
    int*   deg     = (int*)(ws + 0);
    int*   fill    = (int*)(ws + 1000000);
    int*   row_ptr = (int*)(ws + 2000000);
    float* dis     = (float*)(ws + 3000000);
    int*   csr_col = (int*)(ws + 4000000);

    // zero deg + fill (adjacent, one memset)
    hipMemsetAsync(ws, 0, 2000000, stream);

    const int TB = 256;
    const int E4 = N_EDGES / 4;
    count_deg  <<<(E4 + TB - 1) / TB, TB, 0, stream>>>(row, deg);
    compute_dis<<<(N_NODES + TB - 1) / TB, TB, 0, stream>>>(deg, dis);
    scan_rowptr<<<1, 1024, 0, stream>>>(deg, row_ptr);
    fill_csr   <<<(E4 + TB - 1) / TB, TB, 0, stream>>>(row, col, row_ptr, fill, csr_col);

    // output layout: all_feat[i, slot, :] with slot0 = layer3, slot1 = layer1,
    // slot2 = layer2; then final feat (= layer3) at offset 48'000'000.
    int spmm_blocks = (N_NODES + 3) / 4;
    // layer 1: emb -> slot 1
    spmm<<<spmm_blocks, TB, 0, stream>>>(row_ptr, deg, csr_col, dis,
                                         emb, DIM, 0,
                                         out, 3 * DIM, DIM, nullptr);
    // layer 2: slot 1 -> slot 2
    spmm<<<spmm_blocks, TB, 0, stream>>>(row_ptr, deg, csr_col, dis,
                                         out, 3 * DIM, DIM,
                                         out, 3 * DIM, 2 * DIM, nullptr);
    // layer 3: slot 2 -> slot 0  (+ second output)
    spmm<<<spmm_blocks, TB, 0, stream>>>(row_ptr, deg, csr_col, dis,
                                         out, 3 * DIM, 2 * DIM,
                                         out, 3 * DIM, 0, out + 48000000);
}